// Round 1
// 325.188 us; speedup vs baseline: 1.0259x; 1.0259x over previous
//
#include <hip/hip_runtime.h>
#include <math.h>

#define NEG_SLOPE 0.2f

typedef short short8 __attribute__((ext_vector_type(8)));
typedef float floatx4 __attribute__((ext_vector_type(4)));

static __device__ __forceinline__ float bf2f(unsigned short u) {
  return __uint_as_float(((unsigned int)u) << 16);
}
static __device__ __forceinline__ unsigned short f2bf(float f) {
  unsigned int u = __float_as_uint(f);
  u = (u + 0x7fffu + ((u >> 16) & 1u)) >> 16;  // RNE
  return (unsigned short)u;
}
static __device__ __forceinline__ unsigned int pack2(float a, float b) {
  return (unsigned int)f2bf(a) | ((unsigned int)f2bf(b) << 16);
}

// ---------- fused: W1 [512][64] fp32 -> W1t [64][512] bf16  AND deg init ----------
__global__ void init_misc(const float* __restrict__ W1, unsigned short* __restrict__ W1t,
                          int* __restrict__ deg, int N) {
  int b = blockIdx.x;
  if (b < 128) {
    int i = b * 256 + threadIdx.x;  // 32768
    int k = i >> 6, c = i & 63;
    W1t[c * 512 + k] = f2bf(W1[i]);
  } else {
    int n = (b - 128) * 256 + threadIdx.x;
    if (n < N) deg[n] = 1;  // self-loop
  }
}

// ---------- GEMM1 via MFMA, register-prefetched global loads ----------
__global__ __launch_bounds__(256) void gemm1_mfma(const float* __restrict__ A,
                                                  const unsigned short* __restrict__ W1t,
                                                  const float* __restrict__ att_src,
                                                  const float* __restrict__ att_dst,
                                                  unsigned short* __restrict__ xlb,
                                                  float* __restrict__ a_src,
                                                  float* __restrict__ a_dst, int M) {
  __shared__ unsigned short As[64 * 72];  // [row][k], pad 72 (2-way bank alias = free)
  __shared__ unsigned short Bs[64 * 72];  // [col][k]
  int tid = threadIdx.x;
  int w = tid >> 6, lane = tid & 63;
  int q = lane >> 4, cl = lane & 15;
  int row0 = blockIdx.x << 6;
  floatx4 acc[4] = {};

  int sr = tid >> 2;            // staging row/col 0..63
  int skq = (tid & 3) << 4;     // k offset 0,16,32,48
  int arow = row0 + sr;
  bool okA = arow < M;
  const float* Aptr = A + (size_t)arow * 512 + skq;
  const unsigned short* Bptr = W1t + sr * 512 + skq;
  unsigned short* AsW = As + sr * 72 + skq;
  unsigned short* BsW = Bs + sr * 72 + skq;

  // preload tile 0 into registers
  float4 ca0 = make_float4(0.f, 0.f, 0.f, 0.f), ca1 = ca0, ca2 = ca0, ca3 = ca0;
  uint4 cb0, cb1;
  if (okA) {
    ca0 = *(const float4*)(Aptr);
    ca1 = *(const float4*)(Aptr + 4);
    ca2 = *(const float4*)(Aptr + 8);
    ca3 = *(const float4*)(Aptr + 12);
  }
  cb0 = *(const uint4*)(Bptr);
  cb1 = *(const uint4*)(Bptr + 8);

#pragma unroll
  for (int k0 = 0; k0 < 512; k0 += 64) {
    __syncthreads();  // previous MFMA phase done reading LDS
    uint4 a0, a1;
    a0.x = pack2(ca0.x, ca0.y); a0.y = pack2(ca0.z, ca0.w);
    a0.z = pack2(ca1.x, ca1.y); a0.w = pack2(ca1.z, ca1.w);
    a1.x = pack2(ca2.x, ca2.y); a1.y = pack2(ca2.z, ca2.w);
    a1.z = pack2(ca3.x, ca3.y); a1.w = pack2(ca3.z, ca3.w);
    *(uint4*)(AsW) = a0;
    *(uint4*)(AsW + 8) = a1;
    *(uint4*)(BsW) = cb0;
    *(uint4*)(BsW + 8) = cb1;
    __syncthreads();
    // issue next tile's global loads BEFORE MFMA so HBM latency hides under it
    if (k0 < 448) {
      ca0 = make_float4(0.f, 0.f, 0.f, 0.f); ca1 = ca0; ca2 = ca0; ca3 = ca0;
      if (okA) {
        ca0 = *(const float4*)(Aptr + k0 + 64);
        ca1 = *(const float4*)(Aptr + k0 + 68);
        ca2 = *(const float4*)(Aptr + k0 + 72);
        ca3 = *(const float4*)(Aptr + k0 + 76);
      }
      cb0 = *(const uint4*)(Bptr + k0 + 64);
      cb1 = *(const uint4*)(Bptr + k0 + 72);
    }
#pragma unroll
    for (int kk = 0; kk < 2; ++kk) {
      short8 af = *(const short8*)(As + (w * 16 + cl) * 72 + kk * 32 + q * 8);
#pragma unroll
      for (int t = 0; t < 4; ++t) {
        short8 bf = *(const short8*)(Bs + (t * 16 + cl) * 72 + kk * 32 + q * 8);
        acc[t] = __builtin_amdgcn_mfma_f32_16x16x32_bf16(af, bf, acc[t], 0, 0, 0);
      }
    }
  }

  float asv[4], adv[4];
#pragma unroll
  for (int t = 0; t < 4; ++t) {
    asv[t] = att_src[t * 16 + cl];
    adv[t] = att_dst[t * 16 + cl];
  }
#pragma unroll
  for (int reg = 0; reg < 4; ++reg) {
    int r = row0 + w * 16 + q * 4 + reg;
    bool ok = r < M;
#pragma unroll
    for (int t = 0; t < 4; ++t) {
      float v = acc[t][reg];
      if (ok) xlb[(size_t)r * 64 + t * 16 + cl] = f2bf(v);
      float ps = v * asv[t];
      float pd = v * adv[t];
      ps += __shfl_xor(ps, 1); pd += __shfl_xor(pd, 1);
      ps += __shfl_xor(ps, 2); pd += __shfl_xor(pd, 2);
      ps += __shfl_xor(ps, 4); pd += __shfl_xor(pd, 4);
      if (ok && (cl & 7) == 0) {
        int h = t * 2 + (cl >> 3);
        a_src[r * 8 + h] = ps;
        a_dst[r * 8 + h] = pd;
      }
    }
  }
}

// ---------- CSR build ----------
// XCD-sliced histogram: workgroup b handles dst-slice (b&7) on edge chunk (b>>3).
__global__ __launch_bounds__(256) void deg_hist_sliced(const int* __restrict__ ei,
                                                       int* __restrict__ deg,
                                                       int E, int N, int ipc) {
  int slice = blockIdx.x & 7;
  int chunk = blockIdx.x >> 3;
  int lo = (int)(((long long)slice * N) >> 3);
  int hi = (int)(((long long)(slice + 1) * N) >> 3);
  int beg = chunk * ipc;
  int end = min(beg + ipc, E);
  for (int i = beg + threadIdx.x; i < end; i += 256) {
    int d = ei[E + i];
    if (d >= lo && d < hi) atomicAdd(&deg[d], 1);
  }
}

// hierarchical scan, chunk = 512 elements per 256-thread block
__global__ __launch_bounds__(256) void partial_sums(const int* __restrict__ deg,
                                                    int* __restrict__ partials, int N) {
  __shared__ int ws[4];
  int base = blockIdx.x * 512;
  int tid = threadIdx.x;
  int i0 = base + tid * 2;
  int s = 0;
  if (i0 < N) s += deg[i0];
  if (i0 + 1 < N) s += deg[i0 + 1];
#pragma unroll
  for (int off = 32; off >= 1; off >>= 1) s += __shfl_xor(s, off, 64);
  if ((tid & 63) == 0) ws[tid >> 6] = s;
  __syncthreads();
  if (tid == 0) partials[blockIdx.x] = ws[0] + ws[1] + ws[2] + ws[3];
}

__global__ __launch_bounds__(256) void scan_partials(const int* __restrict__ partials,
                                                     int* __restrict__ blockoff,
                                                     int* __restrict__ rowptr, int nb, int N) {
  __shared__ int sums[256];
  int tid = threadIdx.x;
  int chunk = (nb + 255) >> 8;
  int start = tid * chunk, end = min(start + chunk, nb);
  int s = 0;
  for (int i = start; i < end; ++i) s += partials[i];
  sums[tid] = s;
  __syncthreads();
  for (int off = 1; off < 256; off <<= 1) {
    int t = (tid >= off) ? sums[tid - off] : 0;
    __syncthreads();
    sums[tid] += t;
    __syncthreads();
  }
  int run = (tid == 0) ? 0 : sums[tid - 1];
  for (int i = start; i < end; ++i) {
    blockoff[i] = run;
    run += partials[i];
  }
  if (tid == 255) rowptr[N] = sums[255];
}

__global__ __launch_bounds__(256) void scan_blocks(const int* __restrict__ deg,
                                                   const int* __restrict__ blockoff,
                                                   int* __restrict__ rowptr,
                                                   int* __restrict__ cursor, int N) {
  __shared__ int wavesum[4];
  int base = blockIdx.x * 512;
  int tid = threadIdx.x;
  int lane = tid & 63, wv = tid >> 6;
  int i0 = base + tid * 2;
  int d0 = (i0 < N) ? deg[i0] : 0;
  int d1 = (i0 + 1 < N) ? deg[i0 + 1] : 0;
  int s = d0 + d1;
  int v = s;
#pragma unroll
  for (int off = 1; off < 64; off <<= 1) {
    int t = __shfl_up(v, off, 64);
    if (lane >= off) v += t;
  }
  if (lane == 63) wavesum[wv] = v;
  __syncthreads();
  int woff = 0;
  for (int w = 0; w < wv; ++w) woff += wavesum[w];
  int excl = v - s + woff + blockoff[blockIdx.x];
  if (i0 < N) { rowptr[i0] = excl; cursor[i0] = excl; }
  if (i0 + 1 < N) { rowptr[i0 + 1] = excl + d0; cursor[i0 + 1] = excl + d0; }
}

// XCD-sliced scatter: same slicing as deg_hist_sliced.
__global__ __launch_bounds__(256) void scatter_sliced(const int* __restrict__ ei,
                                                      int* __restrict__ cursor,
                                                      int* __restrict__ srcs,
                                                      int E, int N, int ipc) {
  int slice = blockIdx.x & 7;
  int chunk = blockIdx.x >> 3;
  int lo = (int)(((long long)slice * N) >> 3);
  int hi = (int)(((long long)(slice + 1) * N) >> 3);
  int total = E + N;
  int beg = chunk * ipc;
  int end = min(beg + ipc, total);
  for (int i = beg + threadIdx.x; i < end; i += 256) {
    int d = (i < E) ? ei[E + i] : (i - E);
    if (d >= lo && d < hi) {
      int s = (i < E) ? ei[i] : d;
      int pos = atomicAdd(&cursor[d], 1);
      srcs[pos] = s;
    }
  }
}

// ---------- layer-1 aggregation: one 64-lane wave per dst node ----------
// Each lane owns a CHANNEL PAIR (ushort2 loads); the two wave halves process
// two edges concurrently. Halves merged with one shfl_xor(32) at the end.
__global__ __launch_bounds__(256) void agg1_csr(const int* __restrict__ rowptr,
                                                const int* __restrict__ srcs,
                                                const float* __restrict__ a_src,
                                                const float* __restrict__ a_dst,
                                                const unsigned short* __restrict__ xlb,
                                                float* __restrict__ agg1, int N) {
  int wave = (blockIdx.x * blockDim.x + threadIdx.x) >> 6;
  int lane = threadIdx.x & 63;
  if (wave >= N) return;
  int half = lane >> 5;
  int j = lane & 31;       // channel pair index: channels 2j, 2j+1
  int h = j >> 2;          // head of channel 2j
  int beg = rowptr[wave], end = rowptr[wave + 1];
  float ad = a_dst[wave * 8 + h];
  float den = 0.f, acc0 = 0.f, acc1 = 0.f;
  int p = beg;
  for (; p + 4 <= end; p += 4) {  // 4 edges per iter: 2 per half
    int sA = srcs[p + half];
    int sB = srcs[p + 2 + half];
    float aA = a_src[sA * 8 + h] + ad;
    float aB = a_src[sB * 8 + h] + ad;
    ushort2 xA = *(const ushort2*)(xlb + (size_t)sA * 64 + 2 * j);
    ushort2 xB = *(const ushort2*)(xlb + (size_t)sB * 64 + 2 * j);
    aA = aA >= 0.f ? aA : NEG_SLOPE * aA;
    aB = aB >= 0.f ? aB : NEG_SLOPE * aB;
    float wA = __expf(aA), wB = __expf(aB);
    den += wA + wB;
    acc0 += wA * bf2f(xA.x) + wB * bf2f(xB.x);
    acc1 += wA * bf2f(xA.y) + wB * bf2f(xB.y);
  }
  for (; p < end; p += 2) {  // tail: up to 3 edges
    int idx = p + half;
    if (idx < end) {
      int s = srcs[idx];
      float a = a_src[s * 8 + h] + ad;
      ushort2 x = *(const ushort2*)(xlb + (size_t)s * 64 + 2 * j);
      a = a >= 0.f ? a : NEG_SLOPE * a;
      float w = __expf(a);
      den += w;
      acc0 += w * bf2f(x.x);
      acc1 += w * bf2f(x.y);
    }
  }
  den += __shfl_xor(den, 32);
  acc0 += __shfl_xor(acc0, 32);
  acc1 += __shfl_xor(acc1, 32);
  if (half == 0) {
    float inv = 1.f / (den + 1e-16f);
    *(float2*)(agg1 + (size_t)wave * 64 + 2 * j) = make_float2(acc0 * inv, acc1 * inv);
  }
}

// ---------- layer-2 GEMM (bias1 fused) + attention coefs ----------
__global__ __launch_bounds__(256) void gemm2_prep(const float* __restrict__ agg1,
                                                  const float* __restrict__ bias1,
                                                  const float* __restrict__ W2,
                                                  const float* __restrict__ att_src2,
                                                  const float* __restrict__ att_dst2,
                                                  float* __restrict__ xl2,
                                                  float* __restrict__ a_src2,
                                                  float* __restrict__ a_dst2, int N) {
  __shared__ float hs[16 * 68];
  int tid = threadIdx.x;
  int n0 = blockIdx.x << 4;
  {
    int node = tid >> 4;
    int off = (tid & 15) << 2;
    int nn = n0 + node;
    float4 v = make_float4(0.f, 0.f, 0.f, 0.f);
    if (nn < N) {
      v = *(const float4*)(agg1 + (size_t)nn * 64 + off);
      float4 b = *(const float4*)(bias1 + off);
      v.x += b.x; v.y += b.y; v.z += b.z; v.w += b.w;
    }
    *(float4*)(hs + node * 68 + off) = v;
  }
  __syncthreads();
  int t = tid >> 4, c = tid & 15;
  int n = n0 + t;
  if (n >= N) return;
  float sum = 0.f;
#pragma unroll
  for (int k = 0; k < 64; ++k) sum += hs[t * 68 + k] * W2[k * 16 + c];
  xl2[(size_t)n * 16 + c] = sum;
  float ps = sum * att_src2[c];
  float pd = sum * att_dst2[c];
#pragma unroll
  for (int w = 8; w >= 1; w >>= 1) {
    ps += __shfl_xor(ps, w, 16);
    pd += __shfl_xor(pd, w, 16);
  }
  if (c == 0) {
    a_src2[n] = ps;
    a_dst2[n] = pd;
  }
}

// ---------- layer-2 aggregation + bias2 + ELU + log_softmax ----------
__global__ __launch_bounds__(256) void agg2_fin(const int* __restrict__ rowptr,
                                                const int* __restrict__ srcs,
                                                const float* __restrict__ a_src2,
                                                const float* __restrict__ a_dst2,
                                                const float* __restrict__ xl2,
                                                const float* __restrict__ bias2,
                                                float* __restrict__ out, int N) {
  int t = blockIdx.x * blockDim.x + threadIdx.x;
  int node = t >> 4;
  int c = t & 15;
  if (node >= N) return;
  int beg = rowptr[node], end = rowptr[node + 1];
  float ad = a_dst2[node];
  float den = 0.f, acc = 0.f;
  int p = beg;
  for (; p + 4 <= end; p += 4) {
    int s0 = srcs[p], s1 = srcs[p + 1], s2 = srcs[p + 2], s3 = srcs[p + 3];
    float a0 = a_src2[s0], a1 = a_src2[s1], a2 = a_src2[s2], a3 = a_src2[s3];
    float x0 = xl2[(size_t)s0 * 16 + c], x1 = xl2[(size_t)s1 * 16 + c];
    float x2 = xl2[(size_t)s2 * 16 + c], x3 = xl2[(size_t)s3 * 16 + c];
    a0 += ad; a1 += ad; a2 += ad; a3 += ad;
    a0 = a0 >= 0.f ? a0 : NEG_SLOPE * a0;
    a1 = a1 >= 0.f ? a1 : NEG_SLOPE * a1;
    a2 = a2 >= 0.f ? a2 : NEG_SLOPE * a2;
    a3 = a3 >= 0.f ? a3 : NEG_SLOPE * a3;
    float w0 = __expf(a0), w1 = __expf(a1), w2 = __expf(a2), w3 = __expf(a3);
    den += (w0 + w1) + (w2 + w3);
    acc += w0 * x0 + w1 * x1 + w2 * x2 + w3 * x3;
  }
  for (; p < end; ++p) {
    int s = srcs[p];
    float a = a_src2[s] + ad;
    a = a >= 0.f ? a : NEG_SLOPE * a;
    float w = __expf(a);
    den += w;
    acc += w * xl2[(size_t)s * 16 + c];
  }
  float o = acc / (den + 1e-16f) + bias2[c];
  o = o > 0.f ? o : expm1f(o);  // ELU alpha=1
  float mx = o;
#pragma unroll
  for (int w = 8; w >= 1; w >>= 1) mx = fmaxf(mx, __shfl_xor(mx, w, 16));
  float e = __expf(o - mx);
  float ssum = e;
#pragma unroll
  for (int w = 8; w >= 1; w >>= 1) ssum += __shfl_xor(ssum, w, 16);
  out[(size_t)node * 16 + c] = o - mx - logf(ssum);
}

extern "C" void kernel_launch(void* const* d_in, const int* in_sizes, int n_in,
                              void* d_out, int out_size, void* d_ws, size_t ws_size,
                              hipStream_t stream) {
  const float* x        = (const float*)d_in[0];
  const int*   ei       = (const int*)d_in[1];
  const float* W1       = (const float*)d_in[2];
  const float* att_src1 = (const float*)d_in[3];
  const float* att_dst1 = (const float*)d_in[4];
  const float* bias1    = (const float*)d_in[5];
  const float* W2       = (const float*)d_in[6];
  const float* att_src2 = (const float*)d_in[7];
  const float* att_dst2 = (const float*)d_in[8];
  const float* bias2    = (const float*)d_in[9];
  float* out = (float*)d_out;

  int N = in_sizes[0] / 512;
  int E = in_sizes[1] / 2;
  int nb = (N + 511) / 512;

  char* ws = (char*)d_ws;
  unsigned short* xlb = (unsigned short*)ws;        ws += (size_t)N * 64 * 2;
  unsigned short* W1t = (unsigned short*)ws;        ws += (size_t)512 * 64 * 2;
  float* a_src1 = (float*)ws;                       ws += (size_t)N * 8 * 4;
  float* a_dst1 = (float*)ws;                       ws += (size_t)N * 8 * 4;
  float* agg1   = (float*)ws;                       ws += (size_t)N * 64 * 4;
  float* xl2    = (float*)ws;                       ws += (size_t)N * 16 * 4;
  float* a_src2 = (float*)ws;                       ws += (size_t)N * 4;
  float* a_dst2 = (float*)ws;                       ws += (size_t)N * 4;
  int* deg      = (int*)ws;                         ws += (size_t)N * 4;
  int* rowptr   = (int*)ws;                         ws += (size_t)(N + 1) * 4;
  int* cursor   = (int*)ws;                         ws += (size_t)N * 4;
  int* srcs     = (int*)ws;                         ws += (size_t)(E + N) * 4;
  int* partials = (int*)ws;                         ws += (size_t)nb * 4;
  int* blockoff = (int*)ws;                         ws += (size_t)nb * 4;

  // fused init: W1 transpose/convert + deg=1
  init_misc<<<128 + (N + 255) / 256, 256, 0, stream>>>(W1, W1t, deg, N);

  // CSR build (by destination), XCD-sliced to kill write amplification
  const int NCHUNK = 256;
  int ipc_h = (E + NCHUNK - 1) / NCHUNK;
  int ipc_s = (E + N + NCHUNK - 1) / NCHUNK;
  deg_hist_sliced<<<NCHUNK * 8, 256, 0, stream>>>(ei, deg, E, N, ipc_h);
  partial_sums<<<nb, 256, 0, stream>>>(deg, partials, N);
  scan_partials<<<1, 256, 0, stream>>>(partials, blockoff, rowptr, nb, N);
  scan_blocks<<<nb, 256, 0, stream>>>(deg, blockoff, rowptr, cursor, N);
  scatter_sliced<<<NCHUNK * 8, 256, 0, stream>>>(ei, cursor, srcs, E, N, ipc_s);

  // layer 1
  gemm1_mfma<<<(N + 63) / 64, 256, 0, stream>>>(x, W1t, att_src1, att_dst1,
                                                xlb, a_src1, a_dst1, N);
  agg1_csr<<<((size_t)N * 64 + 255) / 256, 256, 0, stream>>>(rowptr, srcs, a_src1, a_dst1,
                                                             xlb, agg1, N);

  // layer 2
  gemm2_prep<<<(N + 15) / 16, 256, 0, stream>>>(agg1, bias1, W2, att_src2, att_dst2,
                                                xl2, a_src2, a_dst2, N);
  agg2_fin<<<((size_t)N * 16 + 255) / 256, 256, 0, stream>>>(rowptr, srcs, a_src2, a_dst2,
                                                             xl2, bias2, out, N);
}

// Round 2
// 311.472 us; speedup vs baseline: 1.0711x; 1.0440x over previous
//
#include <hip/hip_runtime.h>
#include <math.h>

#define NEG_SLOPE 0.2f

typedef short short8 __attribute__((ext_vector_type(8)));
typedef float floatx4 __attribute__((ext_vector_type(4)));

static __device__ __forceinline__ float bf2f(unsigned short u) {
  return __uint_as_float(((unsigned int)u) << 16);
}
static __device__ __forceinline__ unsigned short f2bf(float f) {
  unsigned int u = __float_as_uint(f);
  u = (u + 0x7fffu + ((u >> 16) & 1u)) >> 16;  // RNE
  return (unsigned short)u;
}
static __device__ __forceinline__ unsigned int pack2(float a, float b) {
  return (unsigned int)f2bf(a) | ((unsigned int)f2bf(b) << 16);
}

// ---------- fused: W1 [512][64] fp32 -> W1t [64][512] bf16  AND deg init ----------
__global__ void init_misc(const float* __restrict__ W1, unsigned short* __restrict__ W1t,
                          int* __restrict__ deg, int N) {
  int b = blockIdx.x;
  if (b < 128) {
    int i = b * 256 + threadIdx.x;  // 32768
    int k = i >> 6, c = i & 63;
    W1t[c * 512 + k] = f2bf(W1[i]);
  } else {
    int n = (b - 128) * 256 + threadIdx.x;
    if (n < N) deg[n] = 1;  // self-loop
  }
}

// ---------- FAT kernel: blocks [0,G1) do GEMM1 (MFMA), blocks [G1,..) do deg hist ----------
// The histogram is independent of the GEMM -> its memory/atomic latency hides
// under the MFMA pipe instead of serializing as a separate launch.
__global__ __launch_bounds__(256) void gemm1_hist(const float* __restrict__ A,
                                                  const unsigned short* __restrict__ W1t,
                                                  const float* __restrict__ att_src,
                                                  const float* __restrict__ att_dst,
                                                  unsigned short* __restrict__ xlb,
                                                  float* __restrict__ a_src,
                                                  float* __restrict__ a_dst, int M,
                                                  const int* __restrict__ ei,
                                                  int* __restrict__ deg, int E,
                                                  int ipc, int G1) {
  __shared__ unsigned short As[64 * 72];  // [row][k], pad 72 (2-way bank alias = free)
  __shared__ unsigned short Bs[64 * 72];  // [col][k]
  if ((int)blockIdx.x >= G1) {
    // ---- histogram path (XCD-sliced: same-slice blocks land on one XCD) ----
    int b = blockIdx.x - G1;
    int slice = b & 7;
    int chunk = b >> 3;
    int lo = (int)(((long long)slice * M) >> 3);
    int hi = (int)(((long long)(slice + 1) * M) >> 3);
    int beg = chunk * ipc;
    int end = min(beg + ipc, E);
    for (int i = beg + threadIdx.x; i < end; i += 256) {
      int d = ei[E + i];
      if (d >= lo && d < hi) atomicAdd(&deg[d], 1);
    }
    return;
  }
  // ---- GEMM path ----
  int tid = threadIdx.x;
  int w = tid >> 6, lane = tid & 63;
  int q = lane >> 4, cl = lane & 15;
  int row0 = blockIdx.x << 6;
  floatx4 acc[4] = {};

  int sr = tid >> 2;            // staging row/col 0..63
  int skq = (tid & 3) << 4;     // k offset 0,16,32,48
  int arow = row0 + sr;
  bool okA = arow < M;
  const float* Aptr = A + (size_t)arow * 512 + skq;
  const unsigned short* Bptr = W1t + sr * 512 + skq;
  unsigned short* AsW = As + sr * 72 + skq;
  unsigned short* BsW = Bs + sr * 72 + skq;

  // preload tile 0 into registers
  float4 ca0 = make_float4(0.f, 0.f, 0.f, 0.f), ca1 = ca0, ca2 = ca0, ca3 = ca0;
  uint4 cb0, cb1;
  if (okA) {
    ca0 = *(const float4*)(Aptr);
    ca1 = *(const float4*)(Aptr + 4);
    ca2 = *(const float4*)(Aptr + 8);
    ca3 = *(const float4*)(Aptr + 12);
  }
  cb0 = *(const uint4*)(Bptr);
  cb1 = *(const uint4*)(Bptr + 8);

#pragma unroll
  for (int k0 = 0; k0 < 512; k0 += 64) {
    __syncthreads();  // previous MFMA phase done reading LDS
    uint4 a0, a1;
    a0.x = pack2(ca0.x, ca0.y); a0.y = pack2(ca0.z, ca0.w);
    a0.z = pack2(ca1.x, ca1.y); a0.w = pack2(ca1.z, ca1.w);
    a1.x = pack2(ca2.x, ca2.y); a1.y = pack2(ca2.z, ca2.w);
    a1.z = pack2(ca3.x, ca3.y); a1.w = pack2(ca3.z, ca3.w);
    *(uint4*)(AsW) = a0;
    *(uint4*)(AsW + 8) = a1;
    *(uint4*)(BsW) = cb0;
    *(uint4*)(BsW + 8) = cb1;
    __syncthreads();
    // issue next tile's global loads BEFORE MFMA so HBM latency hides under it
    if (k0 < 448) {
      ca0 = make_float4(0.f, 0.f, 0.f, 0.f); ca1 = ca0; ca2 = ca0; ca3 = ca0;
      if (okA) {
        ca0 = *(const float4*)(Aptr + k0 + 64);
        ca1 = *(const float4*)(Aptr + k0 + 68);
        ca2 = *(const float4*)(Aptr + k0 + 72);
        ca3 = *(const float4*)(Aptr + k0 + 76);
      }
      cb0 = *(const uint4*)(Bptr + k0 + 64);
      cb1 = *(const uint4*)(Bptr + k0 + 72);
    }
#pragma unroll
    for (int kk = 0; kk < 2; ++kk) {
      short8 af = *(const short8*)(As + (w * 16 + cl) * 72 + kk * 32 + q * 8);
#pragma unroll
      for (int t = 0; t < 4; ++t) {
        short8 bf = *(const short8*)(Bs + (t * 16 + cl) * 72 + kk * 32 + q * 8);
        acc[t] = __builtin_amdgcn_mfma_f32_16x16x32_bf16(af, bf, acc[t], 0, 0, 0);
      }
    }
  }

  float asv[4], adv[4];
#pragma unroll
  for (int t = 0; t < 4; ++t) {
    asv[t] = att_src[t * 16 + cl];
    adv[t] = att_dst[t * 16 + cl];
  }
#pragma unroll
  for (int reg = 0; reg < 4; ++reg) {
    int r = row0 + w * 16 + q * 4 + reg;
    bool ok = r < M;
#pragma unroll
    for (int t = 0; t < 4; ++t) {
      float v = acc[t][reg];
      if (ok) xlb[(size_t)r * 64 + t * 16 + cl] = f2bf(v);
      float ps = v * asv[t];
      float pd = v * adv[t];
      ps += __shfl_xor(ps, 1); pd += __shfl_xor(pd, 1);
      ps += __shfl_xor(ps, 2); pd += __shfl_xor(pd, 2);
      ps += __shfl_xor(ps, 4); pd += __shfl_xor(pd, 4);
      if (ok && (cl & 7) == 0) {
        int h = t * 2 + (cl >> 3);
        a_src[r * 8 + h] = ps;
        a_dst[r * 8 + h] = pd;
      }
    }
  }
}

// ---------- single-block exclusive scan of deg -> rowptr, cursor ----------
// One 1024-thread block, 8 elems/thread/pass. Replaces 3 launches; no
// inter-block dependency -> no deadlock risk.
__global__ __launch_bounds__(1024) void scan_single(const int* __restrict__ deg,
                                                    int* __restrict__ rowptr,
                                                    int* __restrict__ cursor, int N) {
  __shared__ int wsum[16];
  int tid = threadIdx.x;
  int lane = tid & 63, wv = tid >> 6;
  int carry = 0;
  for (int base = 0; base < N; base += 8192) {
    int i0 = base + tid * 8;
    int d[8];
    if (i0 + 8 <= N) {
      int4 a = *(const int4*)(deg + i0);
      int4 b = *(const int4*)(deg + i0 + 4);
      d[0] = a.x; d[1] = a.y; d[2] = a.z; d[3] = a.w;
      d[4] = b.x; d[5] = b.y; d[6] = b.z; d[7] = b.w;
    } else {
#pragma unroll
      for (int k = 0; k < 8; ++k) d[k] = (i0 + k < N) ? deg[i0 + k] : 0;
    }
    int e[8];
    e[0] = d[0];
#pragma unroll
    for (int k = 1; k < 8; ++k) e[k] = e[k - 1] + d[k];
    int tot = e[7];
    int v = tot;
#pragma unroll
    for (int off = 1; off < 64; off <<= 1) {
      int t = __shfl_up(v, off, 64);
      if (lane >= off) v += t;
    }
    if (lane == 63) wsum[wv] = v;
    __syncthreads();
    int woff = carry;
    for (int w = 0; w < wv; ++w) woff += wsum[w];
    int excl = woff + v - tot;
    int r[8];
    r[0] = excl;
#pragma unroll
    for (int k = 1; k < 8; ++k) r[k] = excl + e[k - 1];
    if (i0 + 8 <= N) {
      *(int4*)(rowptr + i0)     = make_int4(r[0], r[1], r[2], r[3]);
      *(int4*)(rowptr + i0 + 4) = make_int4(r[4], r[5], r[6], r[7]);
      *(int4*)(cursor + i0)     = make_int4(r[0], r[1], r[2], r[3]);
      *(int4*)(cursor + i0 + 4) = make_int4(r[4], r[5], r[6], r[7]);
    } else {
#pragma unroll
      for (int k = 0; k < 8; ++k)
        if (i0 + k < N) { rowptr[i0 + k] = r[k]; cursor[i0 + k] = r[k]; }
    }
    int bt = 0;
#pragma unroll
    for (int w = 0; w < 16; ++w) bt += wsum[w];
    carry += bt;
    __syncthreads();
  }
  if (tid == 0) rowptr[N] = carry;
}

// XCD-sliced scatter: same slicing as the histogram.
__global__ __launch_bounds__(256) void scatter_sliced(const int* __restrict__ ei,
                                                      int* __restrict__ cursor,
                                                      int* __restrict__ srcs,
                                                      int E, int N, int ipc) {
  int slice = blockIdx.x & 7;
  int chunk = blockIdx.x >> 3;
  int lo = (int)(((long long)slice * N) >> 3);
  int hi = (int)(((long long)(slice + 1) * N) >> 3);
  int total = E + N;
  int beg = chunk * ipc;
  int end = min(beg + ipc, total);
  for (int i = beg + threadIdx.x; i < end; i += 256) {
    int d = (i < E) ? ei[E + i] : (i - E);
    if (d >= lo && d < hi) {
      int s = (i < E) ? ei[i] : d;
      int pos = atomicAdd(&cursor[d], 1);
      srcs[pos] = s;
    }
  }
}

// ---------- layer-1 aggregation FUSED with layer-2 GEMM prep ----------
// One wave per dst node. Lane owns a channel pair; halves process edge batches
// of 4 each (8 edges/wave/iter) with one-batch-ahead srcs prefetch and
// branch-free clamped tails. Epilogue computes xl2 = (h+bias1)@W2 and the
// layer-2 attention dots in-wave (no agg1 round-trip, no gemm2_prep launch).
__global__ __launch_bounds__(256) void agg1_fused(const int* __restrict__ rowptr,
                                                  const int* __restrict__ srcs,
                                                  const float* __restrict__ a_src,
                                                  const float* __restrict__ a_dst,
                                                  const unsigned short* __restrict__ xlb,
                                                  const float* __restrict__ bias1,
                                                  const float* __restrict__ W2,
                                                  const float* __restrict__ att_src2,
                                                  const float* __restrict__ att_dst2,
                                                  float* __restrict__ xl2,
                                                  float* __restrict__ a_src2,
                                                  float* __restrict__ a_dst2, int N) {
  __shared__ float W2s[64 * 16];
  __shared__ float hsm[4][64];
  int tid = threadIdx.x;
  W2s[tid]       = W2[tid];
  W2s[tid + 256] = W2[tid + 256];
  W2s[tid + 512] = W2[tid + 512];
  W2s[tid + 768] = W2[tid + 768];
  __syncthreads();

  int wv = tid >> 6, lane = tid & 63;
  int node = (blockIdx.x << 2) + wv;
  if (node >= N) return;
  int half = lane >> 5;
  int j = lane & 31;   // channel pair index: channels 2j, 2j+1
  int h = j >> 2;      // head of channel 2j
  int beg = rowptr[node], end = rowptr[node + 1];
  float ad = a_dst[node * 8 + h];
  float den = 0.f, acc0 = 0.f, acc1 = 0.f;

  // this half's edges: positions beg+half, beg+half+2, ... (stride 2)
  int p = beg + half;
  bool v0 = p < end, v1 = p + 2 < end, v2 = p + 4 < end, v3 = p + 6 < end;
  int s0 = srcs[v0 ? p : beg];
  int s1 = srcs[v1 ? p + 2 : beg];
  int s2 = srcs[v2 ? p + 4 : beg];
  int s3 = srcs[v3 ? p + 6 : beg];
  while (v0) {
    int np = p + 8;
    bool u0 = np < end, u1 = np + 2 < end, u2 = np + 4 < end, u3 = np + 6 < end;
    int t0 = srcs[u0 ? np : beg];          // prefetch next batch: its latency
    int t1 = srcs[u1 ? np + 2 : beg];      // overlaps this batch's gathers
    int t2 = srcs[u2 ? np + 4 : beg];
    int t3 = srcs[u3 ? np + 6 : beg];
    float a0 = a_src[s0 * 8 + h] + ad;
    float a1 = a_src[s1 * 8 + h] + ad;
    float a2 = a_src[s2 * 8 + h] + ad;
    float a3 = a_src[s3 * 8 + h] + ad;
    ushort2 x0 = *(const ushort2*)(xlb + (size_t)s0 * 64 + 2 * j);
    ushort2 x1 = *(const ushort2*)(xlb + (size_t)s1 * 64 + 2 * j);
    ushort2 x2 = *(const ushort2*)(xlb + (size_t)s2 * 64 + 2 * j);
    ushort2 x3 = *(const ushort2*)(xlb + (size_t)s3 * 64 + 2 * j);
    a0 = a0 >= 0.f ? a0 : NEG_SLOPE * a0;
    a1 = a1 >= 0.f ? a1 : NEG_SLOPE * a1;
    a2 = a2 >= 0.f ? a2 : NEG_SLOPE * a2;
    a3 = a3 >= 0.f ? a3 : NEG_SLOPE * a3;
    float w0 = v0 ? __expf(a0) : 0.f;
    float w1 = v1 ? __expf(a1) : 0.f;
    float w2 = v2 ? __expf(a2) : 0.f;
    float w3 = v3 ? __expf(a3) : 0.f;
    den += (w0 + w1) + (w2 + w3);
    acc0 += w0 * bf2f(x0.x) + w1 * bf2f(x1.x) + w2 * bf2f(x2.x) + w3 * bf2f(x3.x);
    acc1 += w0 * bf2f(x0.y) + w1 * bf2f(x1.y) + w2 * bf2f(x2.y) + w3 * bf2f(x3.y);
    p = np;
    s0 = t0; s1 = t1; s2 = t2; s3 = t3;
    v0 = u0; v1 = u1; v2 = u2; v3 = u3;
  }
  den  += __shfl_xor(den, 32);
  acc0 += __shfl_xor(acc0, 32);
  acc1 += __shfl_xor(acc1, 32);
  float inv = 1.f / (den + 1e-16f);
  float2 bv = *(const float2*)(bias1 + 2 * j);
  float h0 = acc0 * inv + bv.x;
  float h1 = acc1 * inv + bv.y;
  if (half == 0) {
    hsm[wv][2 * j]     = h0;
    hsm[wv][2 * j + 1] = h1;
  }
  // wave-local LDS RAW: same wave, compiler orders via lgkmcnt (may-alias)
  if (lane < 16) {
    float sum = 0.f;
#pragma unroll
    for (int k = 0; k < 64; ++k) sum += hsm[wv][k] * W2s[k * 16 + lane];
    xl2[(size_t)node * 16 + lane] = sum;
    float ps = sum * att_src2[lane];
    float pd = sum * att_dst2[lane];
#pragma unroll
    for (int w = 8; w >= 1; w >>= 1) {
      ps += __shfl_xor(ps, w, 16);
      pd += __shfl_xor(pd, w, 16);
    }
    if (lane == 0) { a_src2[node] = ps; a_dst2[node] = pd; }
  }
}

// ---------- layer-2 aggregation + bias2 + ELU + log_softmax ----------
// 16 lanes per node; clamped 4-edge batches with one-batch-ahead srcs prefetch.
__global__ __launch_bounds__(256) void agg2_fin(const int* __restrict__ rowptr,
                                                const int* __restrict__ srcs,
                                                const float* __restrict__ a_src2,
                                                const float* __restrict__ a_dst2,
                                                const float* __restrict__ xl2,
                                                const float* __restrict__ bias2,
                                                float* __restrict__ out, int N) {
  int t = blockIdx.x * blockDim.x + threadIdx.x;
  int node = t >> 4;
  int c = t & 15;
  if (node >= N) return;
  int beg = rowptr[node], end = rowptr[node + 1];
  float ad = a_dst2[node];
  float den = 0.f, acc = 0.f;
  int p = beg;
  bool v0 = true, v1 = p + 1 < end, v2 = p + 2 < end, v3 = p + 3 < end;
  int s0 = srcs[p];
  int s1 = srcs[v1 ? p + 1 : beg];
  int s2 = srcs[v2 ? p + 2 : beg];
  int s3 = srcs[v3 ? p + 3 : beg];
  while (v0) {
    int np = p + 4;
    bool u0 = np < end, u1 = np + 1 < end, u2 = np + 2 < end, u3 = np + 3 < end;
    int t0 = srcs[u0 ? np : beg];
    int t1 = srcs[u1 ? np + 1 : beg];
    int t2 = srcs[u2 ? np + 2 : beg];
    int t3 = srcs[u3 ? np + 3 : beg];
    float a0 = a_src2[s0] + ad, a1 = a_src2[s1] + ad;
    float a2 = a_src2[s2] + ad, a3 = a_src2[s3] + ad;
    float x0 = xl2[(size_t)s0 * 16 + c], x1 = xl2[(size_t)s1 * 16 + c];
    float x2 = xl2[(size_t)s2 * 16 + c], x3 = xl2[(size_t)s3 * 16 + c];
    a0 = a0 >= 0.f ? a0 : NEG_SLOPE * a0;
    a1 = a1 >= 0.f ? a1 : NEG_SLOPE * a1;
    a2 = a2 >= 0.f ? a2 : NEG_SLOPE * a2;
    a3 = a3 >= 0.f ? a3 : NEG_SLOPE * a3;
    float w0 = v0 ? __expf(a0) : 0.f;
    float w1 = v1 ? __expf(a1) : 0.f;
    float w2 = v2 ? __expf(a2) : 0.f;
    float w3 = v3 ? __expf(a3) : 0.f;
    den += (w0 + w1) + (w2 + w3);
    acc += w0 * x0 + w1 * x1 + w2 * x2 + w3 * x3;
    p = np;
    s0 = t0; s1 = t1; s2 = t2; s3 = t3;
    v0 = u0; v1 = u1; v2 = u2; v3 = u3;
  }
  float o = acc / (den + 1e-16f) + bias2[c];
  o = o > 0.f ? o : expm1f(o);  // ELU alpha=1
  float mx = o;
#pragma unroll
  for (int w = 8; w >= 1; w >>= 1) mx = fmaxf(mx, __shfl_xor(mx, w, 16));
  float e = __expf(o - mx);
  float ssum = e;
#pragma unroll
  for (int w = 8; w >= 1; w >>= 1) ssum += __shfl_xor(ssum, w, 16);
  out[(size_t)node * 16 + c] = o - mx - logf(ssum);
}

static inline size_t rnd16(size_t x) { return (x + 15) & ~(size_t)15; }

extern "C" void kernel_launch(void* const* d_in, const int* in_sizes, int n_in,
                              void* d_out, int out_size, void* d_ws, size_t ws_size,
                              hipStream_t stream) {
  const float* x        = (const float*)d_in[0];
  const int*   ei       = (const int*)d_in[1];
  const float* W1       = (const float*)d_in[2];
  const float* att_src1 = (const float*)d_in[3];
  const float* att_dst1 = (const float*)d_in[4];
  const float* bias1    = (const float*)d_in[5];
  const float* W2       = (const float*)d_in[6];
  const float* att_src2 = (const float*)d_in[7];
  const float* att_dst2 = (const float*)d_in[8];
  const float* bias2    = (const float*)d_in[9];
  float* out = (float*)d_out;

  int N = in_sizes[0] / 512;
  int E = in_sizes[1] / 2;

  char* ws = (char*)d_ws;
  unsigned short* xlb = (unsigned short*)ws;  ws += rnd16((size_t)N * 64 * 2);
  unsigned short* W1t = (unsigned short*)ws;  ws += rnd16((size_t)512 * 64 * 2);
  float* a_src1 = (float*)ws;                 ws += rnd16((size_t)N * 8 * 4);
  float* a_dst1 = (float*)ws;                 ws += rnd16((size_t)N * 8 * 4);
  float* xl2    = (float*)ws;                 ws += rnd16((size_t)N * 16 * 4);
  float* a_src2 = (float*)ws;                 ws += rnd16((size_t)N * 4);
  float* a_dst2 = (float*)ws;                 ws += rnd16((size_t)N * 4);
  int* deg      = (int*)ws;                   ws += rnd16((size_t)N * 4);
  int* rowptr   = (int*)ws;                   ws += rnd16((size_t)(N + 1) * 4);
  int* cursor   = (int*)ws;                   ws += rnd16((size_t)N * 4);
  int* srcs     = (int*)ws;                   ws += rnd16((size_t)(E + N) * 4);

  const int NCHUNK = 256;
  int G1 = (N + 63) / 64;
  int ipc_h = (E + NCHUNK - 1) / NCHUNK;
  int ipc_s = (E + N + NCHUNK - 1) / NCHUNK;

  // 1. init: W1 transpose/convert + deg=1
  init_misc<<<128 + (N + 255) / 256, 256, 0, stream>>>(W1, W1t, deg, N);
  // 2. fat: GEMM1 (MFMA) overlapped with degree histogram
  gemm1_hist<<<G1 + NCHUNK * 8, 256, 0, stream>>>(x, W1t, att_src1, att_dst1,
                                                  xlb, a_src1, a_dst1, N,
                                                  ei, deg, E, ipc_h, G1);
  // 3. single-block scan: deg -> rowptr/cursor
  scan_single<<<1, 1024, 0, stream>>>(deg, rowptr, cursor, N);
  // 4. scatter edges into CSR
  scatter_sliced<<<NCHUNK * 8, 256, 0, stream>>>(ei, cursor, srcs, E, N, ipc_s);
  // 5. layer-1 aggregation + fused layer-2 GEMM/att prep
  agg1_fused<<<(N + 3) / 4, 256, 0, stream>>>(rowptr, srcs, a_src1, a_dst1, xlb,
                                              bias1, W2, att_src2, att_dst2,
                                              xl2, a_src2, a_dst2, N);
  // 6. layer-2 aggregation + epilogue
  agg2_fin<<<((size_t)N * 16 + 255) / 256, 256, 0, stream>>>(rowptr, srcs, a_src2, a_dst2,
                                                             xl2, bias2, out, N);
}